// Round 5
// baseline (433.914 us; speedup 1.0000x reference)
//
#include <hip/hip_runtime.h>

// NoRA: out = P(x) / (1 + |Z(x)*x|), per-group coefficients adapted by LoRA.
// B=4, L=4096, D=4096, G=8, Dg=512, R=3. All tensors fp32.
// Memory-bound: 256 MB in + 256 MB out => kernel roofline ~85 us @ 6.3 TB/s
// (m13 mixed-copy ceiling). Timed score also contains 2x ~165 us harness
// poison fills => score floor ~412 us.
//
// Round-ledger:
//  R1 (hoist/unroll/nt on grid-stride):          444.6 (null vs 444.8)
//  R2 (contiguous 128 KiB tiles + nt):           434.5 (geometry WIN -10)
//  R3 (tiles, nt removed — isolation):           441.0 (nt is a +6.5 WIN)
//  R4 (8-load burst -> compute -> 8-store):      431.2 (burst WIN -3.3)
//  R5 (this): burst 8 -> 16 per thread. 512-thread blocks x 16 float4
//     (tile still 128 KiB, grid still 2048). Per-wave pure-read burst
//     16 KiB, then pure-write 16 KiB. launch_bounds(512,4) pins VGPR<=128
//     => 16 waves/CU (2 blocks resident). Group alternates with chunk
//     parity: even chunks g=tid>>7 (0..3), odd chunks g+4 (4..7); both
//     coeff sets in registers, parity resolved at compile time.

#define NG 6   // numerator coeffs per group
#define DG 4   // denominator coeffs per group
#define GROUPS 8
#define RANK 3
#define SCALING 2.0f
#define EPS 1e-6f

typedef float f4 __attribute__((ext_vector_type(4)));

__device__ __forceinline__ float rat1(float xv,
                                      float a0, float a1, float a2,
                                      float a3, float a4, float a5,
                                      float b0, float b1, float b2, float b3)
{
    // P(x) = a0 + a1 x + ... + a5 x^5 (Horner)
    float p = fmaf(a5, xv, a4);
    p = fmaf(p, xv, a3);
    p = fmaf(p, xv, a2);
    p = fmaf(p, xv, a1);
    p = fmaf(p, xv, a0);
    // Z(x) = b0 + b1 x + b2 x^2 + b3 x^3 (Horner); Q = 1 + |Z*x|
    float z = fmaf(b3, xv, b2);
    z = fmaf(z, xv, b1);
    z = fmaf(z, xv, b0);
    const float q = 1.0f + fabsf(z * xv);
    return p * __builtin_amdgcn_rcpf(q);
}

__device__ __forceinline__ f4 rat4(f4 in,
                                   float a0, float a1, float a2,
                                   float a3, float a4, float a5,
                                   float b0, float b1, float b2, float b3)
{
    f4 o;
    o.x = rat1(in.x, a0, a1, a2, a3, a4, a5, b0, b1, b2, b3);
    o.y = rat1(in.y, a0, a1, a2, a3, a4, a5, b0, b1, b2, b3);
    o.z = rat1(in.z, a0, a1, a2, a3, a4, a5, b0, b1, b2, b3);
    o.w = rat1(in.w, a0, a1, a2, a3, a4, a5, b0, b1, b2, b3);
    return o;
}

#define THREADS 512
#define VPT 16                           // float4 per thread
#define VEC_PER_BLOCK (THREADS * VPT)    // 8192 vectors = 128 KiB tile
#define CHUNK THREADS                    // 512 vectors per chunk

__global__ __launch_bounds__(THREADS, 4) void nora_kernel(
    const float* __restrict__ x,          // [B*L*D]
    const float* __restrict__ base_num,   // [G,6]
    const float* __restrict__ base_den,   // [G,4]
    const float* __restrict__ lA_num,     // [R,6]
    const float* __restrict__ lB_num,     // [G,R]
    const float* __restrict__ lA_den,     // [R,4]
    const float* __restrict__ lB_den,     // [G,R]
    float* __restrict__ out,
    int n_vec)                            // total / 4
{
    __shared__ float s_num[GROUPS][NG];
    __shared__ float s_den[GROUPS][DG];

    const int tid = threadIdx.x;
    if (tid < GROUPS * NG) {                       // 48 threads: numerator coeffs
        const int g = tid / NG, k = tid % NG;
        float s = 0.f;
        #pragma unroll
        for (int r = 0; r < RANK; ++r)
            s += lB_num[g * RANK + r] * lA_num[r * NG + k];
        s_num[g][k] = base_num[tid] + SCALING * s;
    } else if (tid < GROUPS * NG + GROUPS * DG) {  // 32 threads: denominator coeffs
        const int t = tid - GROUPS * NG;
        const int g = t / DG, k = t % DG;
        float s = 0.f;
        #pragma unroll
        for (int r = 0; r < RANK; ++r)
            s += lB_den[g * RANK + r] * lA_den[r * DG + k];
        s_den[g][k] = base_den[t] + SCALING * s + EPS;
    }
    __syncthreads();

    // v = base + j*512 + tid, base % 1024 == 0, tid < 512:
    //   v mod 1024 = tid + 512*(j&1)  =>  group = (tid>>7) + 4*(j&1).
    // Even chunks: gA = tid>>7 in 0..3; odd chunks: gB = gA+4 in 4..7.
    // Wave-uniform (tid>>7 constant within a 64-lane wave).
    const int gA = tid >> 7;
    const int gB = gA + 4;
    const float aA0 = s_num[gA][0], aA1 = s_num[gA][1], aA2 = s_num[gA][2];
    const float aA3 = s_num[gA][3], aA4 = s_num[gA][4], aA5 = s_num[gA][5];
    const float bA0 = s_den[gA][0], bA1 = s_den[gA][1];
    const float bA2 = s_den[gA][2], bA3 = s_den[gA][3];
    const float aB0 = s_num[gB][0], aB1 = s_num[gB][1], aB2 = s_num[gB][2];
    const float aB3 = s_num[gB][3], aB4 = s_num[gB][4], aB5 = s_num[gB][5];
    const float bB0 = s_den[gB][0], bB1 = s_den[gB][1];
    const float bB2 = s_den[gB][2], bB3 = s_den[gB][3];

    const f4* __restrict__ xv4 = (const f4*)x;
    f4* __restrict__ ov4 = (f4*)out;

    const int base = blockIdx.x * VEC_PER_BLOCK;

    if (base + VEC_PER_BLOCK <= n_vec) {
        // Full tile: 16-load pure-read burst -> compute -> 16-store
        // pure-write burst. Fully unrolled => all t[] indices are
        // compile-time constants (registers, no scratch — rule #20).
        const int v0 = base + tid;
        f4 t[VPT];
        #pragma unroll
        for (int j = 0; j < VPT; ++j)
            t[j] = __builtin_nontemporal_load(xv4 + v0 + j * CHUNK);
        #pragma unroll
        for (int j = 0; j < VPT; ++j) {
            if ((j & 1) == 0)
                t[j] = rat4(t[j], aA0, aA1, aA2, aA3, aA4, aA5,
                                  bA0, bA1, bA2, bA3);
            else
                t[j] = rat4(t[j], aB0, aB1, aB2, aB3, aB4, aB5,
                                  bB0, bB1, bB2, bB3);
        }
        #pragma unroll
        for (int j = 0; j < VPT; ++j)
            __builtin_nontemporal_store(t[j], ov4 + v0 + j * CHUNK);
    } else {
        // Partial last tile (not taken at shipped shape: n_vec = 2048*8192).
        for (int j = 0; j < VPT; ++j) {
            const int v = base + j * CHUNK + tid;
            if (v < n_vec) {
                const int g = (gA + ((j & 1) << 2)) & (GROUPS - 1);
                const f4 i = __builtin_nontemporal_load(xv4 + v);
                __builtin_nontemporal_store(
                    rat4(i, s_num[g][0], s_num[g][1], s_num[g][2],
                            s_num[g][3], s_num[g][4], s_num[g][5],
                            s_den[g][0], s_den[g][1], s_den[g][2],
                            s_den[g][3]),
                    ov4 + v);
            }
        }
    }
}

extern "C" void kernel_launch(void* const* d_in, const int* in_sizes, int n_in,
                              void* d_out, int out_size, void* d_ws, size_t ws_size,
                              hipStream_t stream) {
    const float* x   = (const float*)d_in[0];
    const float* bn  = (const float*)d_in[1];
    const float* bd  = (const float*)d_in[2];
    const float* lAn = (const float*)d_in[3];
    const float* lBn = (const float*)d_in[4];
    const float* lAd = (const float*)d_in[5];
    const float* lBd = (const float*)d_in[6];
    float* out = (float*)d_out;

    const int n = in_sizes[0];          // 4*4096*4096 = 67108864, divisible by 4
    const int n_vec = n / 4;            // 16777216 float4 vectors

    const int grid = (n_vec + VEC_PER_BLOCK - 1) / VEC_PER_BLOCK;  // 2048
    hipLaunchKernelGGL(nora_kernel, dim3(grid), dim3(THREADS), 0, stream,
                       x, bn, bd, lAn, lBn, lAd, lBd, out, n_vec);
}

// Round 6
// 429.644 us; speedup vs baseline: 1.0099x; 1.0099x over previous
//
#include <hip/hip_runtime.h>

// NoRA: out = P(x) / (1 + |Z(x)*x|), per-group coefficients adapted by LoRA.
// B=4, L=4096, D=4096, G=8, Dg=512, R=3. All tensors fp32.
// Memory-bound: 256 MB in + 256 MB out => kernel roofline ~85 us @ 6.3 TB/s
// (m13 mixed-copy ceiling). Timed score also contains 2x ~165 us harness
// poison fills => score floor ~412 us.
//
// Round-ledger:
//  R1 (hoist/unroll/nt on grid-stride):          444.6 (null vs 444.8)
//  R2 (contiguous 128 KiB tiles + nt):           434.5 (geometry WIN -10)
//  R3 (tiles, nt removed — isolation):           441.0 (nt is a +6.5 WIN)
//  R4 (8-load burst -> compute -> 8-store):      431.2 (burst WIN -3.3)
//  R5 (burst 16, 512 thr):                       433.9 (REGRESS +2.7 —
//     occupancy 32->16 waves/CU offset longer bursts; lever saturated)
//  R6 (this): restore R4 exactly — best measured config. Kernel segment
//     ~101 us ~ 5.3 TB/s vs 6.29 TB/s mixed-copy ceiling; remaining gap
//     is R/W turnaround no access pattern removed. 76% of score is
//     harness poison-fill traffic. This is the practical roofline.

#define NG 6   // numerator coeffs per group
#define DG 4   // denominator coeffs per group
#define GROUPS 8
#define RANK 3
#define SCALING 2.0f
#define EPS 1e-6f

typedef float f4 __attribute__((ext_vector_type(4)));

__device__ __forceinline__ float rat1(float xv,
                                      float a0, float a1, float a2,
                                      float a3, float a4, float a5,
                                      float b0, float b1, float b2, float b3)
{
    // P(x) = a0 + a1 x + ... + a5 x^5 (Horner)
    float p = fmaf(a5, xv, a4);
    p = fmaf(p, xv, a3);
    p = fmaf(p, xv, a2);
    p = fmaf(p, xv, a1);
    p = fmaf(p, xv, a0);
    // Z(x) = b0 + b1 x + b2 x^2 + b3 x^3 (Horner); Q = 1 + |Z*x|
    float z = fmaf(b3, xv, b2);
    z = fmaf(z, xv, b1);
    z = fmaf(z, xv, b0);
    const float q = 1.0f + fabsf(z * xv);
    return p * __builtin_amdgcn_rcpf(q);
}

__device__ __forceinline__ f4 rat4(f4 in,
                                   float a0, float a1, float a2,
                                   float a3, float a4, float a5,
                                   float b0, float b1, float b2, float b3)
{
    f4 o;
    o.x = rat1(in.x, a0, a1, a2, a3, a4, a5, b0, b1, b2, b3);
    o.y = rat1(in.y, a0, a1, a2, a3, a4, a5, b0, b1, b2, b3);
    o.z = rat1(in.z, a0, a1, a2, a3, a4, a5, b0, b1, b2, b3);
    o.w = rat1(in.w, a0, a1, a2, a3, a4, a5, b0, b1, b2, b3);
    return o;
}

#define VEC_PER_BLOCK 8192   // 1024 threads x 8 float4 = 128 KiB tile
#define CHUNK 1024           // vectors per chunk = one group period

__global__ __launch_bounds__(1024) void nora_kernel(
    const float* __restrict__ x,          // [B*L*D]
    const float* __restrict__ base_num,   // [G,6]
    const float* __restrict__ base_den,   // [G,4]
    const float* __restrict__ lA_num,     // [R,6]
    const float* __restrict__ lB_num,     // [G,R]
    const float* __restrict__ lA_den,     // [R,4]
    const float* __restrict__ lB_den,     // [G,R]
    float* __restrict__ out,
    int n_vec)                            // total / 4
{
    __shared__ float s_num[GROUPS][NG];
    __shared__ float s_den[GROUPS][DG];

    const int tid = threadIdx.x;
    if (tid < GROUPS * NG) {                       // 48 threads: numerator coeffs
        const int g = tid / NG, k = tid % NG;
        float s = 0.f;
        #pragma unroll
        for (int r = 0; r < RANK; ++r)
            s += lB_num[g * RANK + r] * lA_num[r * NG + k];
        s_num[g][k] = base_num[tid] + SCALING * s;
    } else if (tid < GROUPS * NG + GROUPS * DG) {  // 32 threads: denominator coeffs
        const int t = tid - GROUPS * NG;
        const int g = t / DG, k = t % DG;
        float s = 0.f;
        #pragma unroll
        for (int r = 0; r < RANK; ++r)
            s += lB_den[g * RANK + r] * lA_den[r * DG + k];
        s_den[g][k] = base_den[t] + SCALING * s + EPS;
    }
    __syncthreads();

    // v = base + j*1024 + tid with base % 1024 == 0
    //   => group = (v>>7)&7 = (tid>>7)&7, identical for every chunk j.
    // Wave-uniform (tid>>7 constant within a 64-lane wave).
    const int g = (tid >> 7) & (GROUPS - 1);
    const float a0 = s_num[g][0], a1 = s_num[g][1], a2 = s_num[g][2];
    const float a3 = s_num[g][3], a4 = s_num[g][4], a5 = s_num[g][5];
    const float b0 = s_den[g][0], b1 = s_den[g][1];
    const float b2 = s_den[g][2], b3 = s_den[g][3];

    const f4* __restrict__ xv4 = (const f4*)x;
    f4* __restrict__ ov4 = (f4*)out;

    const int base = blockIdx.x * VEC_PER_BLOCK;

    if (base + VEC_PER_BLOCK <= n_vec) {
        // Full tile, single pass: 8-load burst -> compute -> 8-store burst.
        // Per wave: one 8 KiB pure-read burst then one 8 KiB pure-write
        // burst. nt: zero-reuse stream, keep it out of L2/MALL (R3
        // isolated nt as a +6.5 us win).
        const int v0 = base + tid;
        f4 t0, t1, t2, t3, t4, t5, t6, t7;
        t0 = __builtin_nontemporal_load(xv4 + v0);
        t1 = __builtin_nontemporal_load(xv4 + v0 + 1 * CHUNK);
        t2 = __builtin_nontemporal_load(xv4 + v0 + 2 * CHUNK);
        t3 = __builtin_nontemporal_load(xv4 + v0 + 3 * CHUNK);
        t4 = __builtin_nontemporal_load(xv4 + v0 + 4 * CHUNK);
        t5 = __builtin_nontemporal_load(xv4 + v0 + 5 * CHUNK);
        t6 = __builtin_nontemporal_load(xv4 + v0 + 6 * CHUNK);
        t7 = __builtin_nontemporal_load(xv4 + v0 + 7 * CHUNK);

        t0 = rat4(t0, a0, a1, a2, a3, a4, a5, b0, b1, b2, b3);
        t1 = rat4(t1, a0, a1, a2, a3, a4, a5, b0, b1, b2, b3);
        t2 = rat4(t2, a0, a1, a2, a3, a4, a5, b0, b1, b2, b3);
        t3 = rat4(t3, a0, a1, a2, a3, a4, a5, b0, b1, b2, b3);
        t4 = rat4(t4, a0, a1, a2, a3, a4, a5, b0, b1, b2, b3);
        t5 = rat4(t5, a0, a1, a2, a3, a4, a5, b0, b1, b2, b3);
        t6 = rat4(t6, a0, a1, a2, a3, a4, a5, b0, b1, b2, b3);
        t7 = rat4(t7, a0, a1, a2, a3, a4, a5, b0, b1, b2, b3);

        __builtin_nontemporal_store(t0, ov4 + v0);
        __builtin_nontemporal_store(t1, ov4 + v0 + 1 * CHUNK);
        __builtin_nontemporal_store(t2, ov4 + v0 + 2 * CHUNK);
        __builtin_nontemporal_store(t3, ov4 + v0 + 3 * CHUNK);
        __builtin_nontemporal_store(t4, ov4 + v0 + 4 * CHUNK);
        __builtin_nontemporal_store(t5, ov4 + v0 + 5 * CHUNK);
        __builtin_nontemporal_store(t6, ov4 + v0 + 6 * CHUNK);
        __builtin_nontemporal_store(t7, ov4 + v0 + 7 * CHUNK);
    } else {
        // Partial last tile (not taken at shipped shape: n_vec = 2048*8192).
        for (int j = 0; j < 8; ++j) {
            const int v = base + j * CHUNK + tid;
            if (v < n_vec) {
                const f4 i = __builtin_nontemporal_load(xv4 + v);
                __builtin_nontemporal_store(
                    rat4(i, a0, a1, a2, a3, a4, a5, b0, b1, b2, b3), ov4 + v);
            }
        }
    }
}

extern "C" void kernel_launch(void* const* d_in, const int* in_sizes, int n_in,
                              void* d_out, int out_size, void* d_ws, size_t ws_size,
                              hipStream_t stream) {
    const float* x   = (const float*)d_in[0];
    const float* bn  = (const float*)d_in[1];
    const float* bd  = (const float*)d_in[2];
    const float* lAn = (const float*)d_in[3];
    const float* lBn = (const float*)d_in[4];
    const float* lAd = (const float*)d_in[5];
    const float* lBd = (const float*)d_in[6];
    float* out = (float*)d_out;

    const int n = in_sizes[0];          // 4*4096*4096 = 67108864, divisible by 4
    const int n_vec = n / 4;            // 16777216 float4 vectors

    const int block = 1024;
    const int grid  = (n_vec + VEC_PER_BLOCK - 1) / VEC_PER_BLOCK;  // 2048
    hipLaunchKernelGGL(nora_kernel, dim3(grid), dim3(block), 0, stream,
                       x, bn, bd, lAn, lBn, lAd, lBd, out, n_vec);
}